// Round 11
// baseline (163.091 us; speedup 1.0000x reference)
//
#include <hip/hip_runtime.h>
#include <stdint.h>

// ---------------- problem constants (from reference) ----------------
constexpr int NN   = 20000;          // N_NODES
constexpr int DD   = 8;              // D
constexpr int ND   = NN * DD;        // 160000 block-rows
constexpr uint32_t HSIZE = 1u << 20; // 1,048,576 slots for 500k keys
constexpr uint32_t HMASK = HSIZE - 1;
// packed slot: (key << 19) | edge_idx.  key < 2^29, idx < 2^19. EMPTY = all-ones.
constexpr unsigned long long EMPTY64 = ~0ULL;

typedef float v4f __attribute__((ext_vector_type(4)));

__device__ __forceinline__ uint32_t hkey(uint32_t k) {
    k *= 2654435761u;
    return k ^ (k >> 15);
}

__device__ __forceinline__ int hprobe(const unsigned long long* __restrict__ slots,
                                      uint32_t key, int fallback) {
    uint32_t s = hkey(key) & HMASK;
    while (true) {
        unsigned long long v = slots[s];
        if (v == EMPTY64) return fallback;
        if ((uint32_t)(v >> 19) == key) return (int)(v & 0x7FFFFu);
        s = (s + 1) & HMASK;
    }
}

// 8x8 MAC: acc[k] += F_a[j][i] * F_b[j][k]  (P = A^T B, lane owns row i)
__device__ __forceinline__ void mac8(const float* __restrict__ fav,
                                     const float* __restrict__ fbv,
                                     int i, float* __restrict__ acc) {
#pragma unroll
    for (int j = 0; j < 8; ++j) {
        float  a  = fav[j * 8 + i];
        float4 b0 = *(const float4*)&fbv[j * 8];
        float4 b1 = *(const float4*)&fbv[j * 8 + 4];
        acc[0] = fmaf(a, b0.x, acc[0]);  acc[1] = fmaf(a, b0.y, acc[1]);
        acc[2] = fmaf(a, b0.z, acc[2]);  acc[3] = fmaf(a, b0.w, acc[3]);
        acc[4] = fmaf(a, b1.x, acc[4]);  acc[5] = fmaf(a, b1.y, acc[5]);
        acc[6] = fmaf(a, b1.z, acc[6]);  acc[7] = fmaf(a, b1.w, acc[7]);
    }
}

// ---------------- fill: slots=EMPTY (16B), deg=1, flags=0 -----------------
__global__ void k_fill(unsigned long long* __restrict__ slots,
                       float* __restrict__ deg, uint32_t* __restrict__ flags,
                       int nflag) {
    uint32_t i = blockIdx.x * blockDim.x + threadIdx.x;
    if (i < HSIZE / 2) {
        ulonglong2 v; v.x = EMPTY64; v.y = EMPTY64;
        ((ulonglong2*)slots)[i] = v;
    }
    if (i < (uint32_t)ND) deg[i] = 1.0f;
    if (i < (uint32_t)nflag) flags[i] = 0u;
}

// ---------------- co-scheduled: insert blocks ∥ optimistic pairdeg blocks -
// Role mapping: bid%M==0 && bid/M<NBI -> insert block (bid/M); else deg
// block. Insert (atomic-bound, ~0 BW) hides under pairdeg (HBM-bound).
// Insert role: Robin-Hood atomicMin64 + duplicate flagging (R8-validated).
// Deg role: optimistic P = F_p^T F_{p+EH}; rowsum|P|->deg[row], butterfly
// colsum->deg[col]. Repaired exactly by k_fixdeg for flagged edges.
__global__ void __launch_bounds__(256)
k_work(const float* __restrict__ F,
       const int* __restrict__ row, const int* __restrict__ col,
       unsigned long long* __restrict__ slots, uint32_t* __restrict__ flags,
       float* __restrict__ deg, int E, int EH, int NBI, int M) {
    __shared__ float fa[64 * 68];
    __shared__ int s_row[32], s_col[32];
    const int t   = threadIdx.x;
    const int bid = blockIdx.x;
    const int q   = bid / M, r = bid % M;

    if (r == 0 && q < NBI) {                       // ---- insert role ----
        int e = q * 256 + t;
        if (e < E) {
            uint32_t key = (uint32_t)(row[e] * NN + col[e]);
            unsigned long long cur = ((unsigned long long)key << 19) | (unsigned)e;
            uint32_t s = hkey(key) & HMASK;
            while (true) {
                unsigned long long old = atomicMin(&slots[s], cur);
                if (old == EMPTY64) break;
                if ((uint32_t)(old >> 19) == key) {           // dup meeting
                    int a = (int)(old & 0x7FFFFu), b = (int)(cur & 0x7FFFFu);
                    atomicOr(&flags[a >> 5], 1u << (a & 31));
                    atomicOr(&flags[b >> 5], 1u << (b & 31));
                    break;
                }
                if (old > cur) { cur = old; key = (uint32_t)(cur >> 19); }
                s = (s + 1) & HMASK;
            }
        }
        return;
    }

    // ---- deg role (R8 k_pairdeg body, dblk-indexed) ----
    const int ic   = min(q + (r ? 1 : 0), NBI);    // insert blocks before bid
    const int dblk = bid - ic;
    const int b0   = dblk * 32;
    const int np   = min(32, EH - b0);

    if (t < 32 && t < np) { s_row[t] = row[b0 + t]; s_col[t] = col[b0 + t]; }
    const float4* F4 = (const float4*)F;
#pragma unroll
    for (int p = 0; p < 4; ++p) {
        int qq = t + p * 256;                      // 0..1023
        int sl = qq >> 4, sub = qq & 15, pi = sl & 31;
        if (pi < np) {
            int x = b0 + pi + ((sl & 32) ? EH : 0);
            *(float4*)&fa[sl * 68 + (sub << 2)] = F4[(size_t)x * 16 + sub];
        }
    }
    __syncthreads();

    const int g = t >> 3, i = t & 7;
    if (g >= np) return;
    float acc[8] = {0,0,0,0,0,0,0,0};
    mac8(&fa[g * 68], &fa[(g + 32) * 68], i, acc);
    float b0f = fabsf(acc[0]), b1 = fabsf(acc[1]), b2 = fabsf(acc[2]), b3 = fabsf(acc[3]);
    float b4  = fabsf(acc[4]), b5 = fabsf(acc[5]), b6 = fabsf(acc[6]), b7 = fabsf(acc[7]);
    float rs  = b0f + b1 + b2 + b3 + b4 + b5 + b6 + b7;
    atomicAdd(&deg[s_row[g] * DD + i], rs);        // edge p row contribution
#pragma unroll
    for (int m = 1; m < 8; m <<= 1) {              // colsum = partner's rowsum
        b0f += __shfl_xor(b0f, m); b1 += __shfl_xor(b1, m);
        b2  += __shfl_xor(b2, m);  b3 += __shfl_xor(b3, m);
        b4  += __shfl_xor(b4, m);  b5 += __shfl_xor(b5, m);
        b6  += __shfl_xor(b6, m);  b7 += __shfl_xor(b7, m);
    }
    float ci = (i & 4) ? ((i & 2) ? ((i & 1) ? b7 : b6) : ((i & 1) ? b5 : b4))
                       : ((i & 2) ? ((i & 1) ? b3 : b2) : ((i & 1) ? b1 : b0f));
    atomicAdd(&deg[s_col[g] * DD + i], ci);        // edge p+EH row contribution
}

// ---------------- repair deg for dup-affected edges (~hundreds) -----------
// rev[e] != partner only possible if partner's key is duplicated (flagged).
__global__ void k_fixdeg(const float* __restrict__ F, const int* __restrict__ row,
                         const int* __restrict__ col,
                         const unsigned long long* __restrict__ slots,
                         const uint32_t* __restrict__ flags,
                         float* __restrict__ deg, int E, int EH) {
    int e = blockIdx.x * blockDim.x + threadIdx.x;
    if (e >= E) return;
    bool tail = (e == 2 * EH);                     // odd-E safety (unused here)
    int partner = tail ? e : ((e < EH) ? e + EH : e - EH);
    if (!tail && !((flags[partner >> 5] >> (partner & 31)) & 1u)) return;
    int r = row[e], c = col[e];
    int f = hprobe(slots, (uint32_t)(c * NN + r), e);
    if (!tail && f == partner) return;             // optimistic was right
    const float* Fe = F + (size_t)e * 64;
    const float* Ff = F + (size_t)f * 64;
    const float* Fp = F + (size_t)partner * 64;
    for (int i = 0; i < 8; ++i) {
        float s1 = 0.f, s2 = 0.f;
        for (int k = 0; k < 8; ++k) {
            float p1 = 0.f, p2 = 0.f;
            for (int j = 0; j < 8; ++j) {
                float a = Fe[j * 8 + i];
                p1 = fmaf(a, Ff[j * 8 + k], p1);
                p2 = fmaf(a, Fp[j * 8 + k], p2);
            }
            s1 += fabsf(p1); s2 += fabsf(p2);
        }
        atomicAdd(&deg[r * DD + i], tail ? s1 : (s1 - s2));
    }
}

// ---------------- dinv = deg^-0.5 AND diagonal blocks of out --------------
__global__ void k_dinv_diag(const float* __restrict__ deg, float* __restrict__ dinv,
                            float* __restrict__ out, int E) {
    int r = blockIdx.x * blockDim.x + threadIdx.x;
    if (r >= ND) return;
    float dv = 1.0f / sqrtf(deg[r]);
    dinv[r] = dv;
    float dd = dv * dv;
    int i = r & 7;
    v4f a = { 0.f, 0.f, 0.f, 0.f };
    v4f b = { 0.f, 0.f, 0.f, 0.f };
    if (i < 4) a[i] = dd; else b[i - 4] = dd;
    size_t base = (size_t)E * 64 + (size_t)(r >> 3) * 64 + (size_t)i * 8;
    __builtin_nontemporal_store(a, (v4f*)&out[base]);
    __builtin_nontemporal_store(b, (v4f*)&out[base + 4]);
}

// ---------------- pass B: inline flag-gated classify + normalize + write --
__global__ void __launch_bounds__(256)
k_pnorm_opt(const float* __restrict__ F,
            const int* __restrict__ row, const int* __restrict__ col,
            const unsigned long long* __restrict__ slots,
            const uint32_t* __restrict__ flags, const float* __restrict__ dinv,
            float* __restrict__ out, int E, int EH) {
    __shared__ float fa[64 * 68];
    __shared__ int s_x[64], s_f[64], s_cls[64], s_row[64], s_col[64];
    const int t  = threadIdx.x;
    const int b0 = blockIdx.x * 32;

    if (t < 64) {
        int s = t;
        int half2 = (s >= 32) ? 1 : 0;
        int pi = s & 31;
        int x = b0 + pi + (half2 ? EH : 0);
        int cls = 0, f = 0, r = 0, c = 0;
        if (b0 + pi < EH) {
            r = row[x]; c = col[x];
            int p = half2 ? x - EH : x + EH;
            uint32_t fl = ((flags[x >> 5] >> (x & 31)) |
                           (flags[p >> 5] >> (p & 31))) & 1u;
            if (!fl) {                              // clean pair: rev=partner
                f = p; cls = half2 ? 0 : 2;         // x<f always in first half
            } else {                                // exact fallback (rare)
                f = hprobe(slots, (uint32_t)(c * NN + r), x);
                int me = hprobe(slots, (uint32_t)(r * NN + c), x);
                cls = (f == x) ? 1 : ((me == x) ? ((x < f) ? 2 : 0) : 1);
            }
        } else x = -1;
        s_x[s] = x; s_f[s] = f; s_cls[s] = cls; s_row[s] = r; s_col[s] = c;
    }
    __syncthreads();

    const float4* F4 = (const float4*)F;
#pragma unroll
    for (int p = 0; p < 4; ++p) {
        int qq = t + p * 256;
        int sl = qq >> 4, sub = qq & 15;
        int x = s_x[sl];
        if (x >= 0)
            *(float4*)&fa[sl * 68 + (sub << 2)] = F4[(size_t)x * 16 + sub];
    }
    __syncthreads();

    const int g = t >> 3, i = t & 7;
#pragma unroll
    for (int item = 0; item < 2; ++item) {
        int s = item ? (g + 32) : g;
        int q = s ^ 32;
        int x = s_x[s];
        int cls = (x >= 0) ? s_cls[s] : 0;
        if (cls) {
            int f = s_f[s];
            const float* fav = &fa[s * 68];
            float acc[8] = {0,0,0,0,0,0,0,0};
            const float* lsrc = (f == s_x[q]) ? &fa[q * 68] : ((f == x) ? fav : nullptr);
            if (lsrc) mac8(fav, lsrc, i, acc);
            else      mac8(fav, F + (size_t)f * 64, i, acc);   // rare (dups)

            const int r = s_row[s], c = s_col[s];
            float dr = dinv[r * DD + i];
            v4f dc0 = *(const v4f*)&dinv[c * DD];
            v4f dc1 = *(const v4f*)&dinv[c * DD + 4];

            float v[8];
            v[0]=acc[0]*dr*dc0.x; v[1]=acc[1]*dr*dc0.y;
            v[2]=acc[2]*dr*dc0.z; v[3]=acc[3]*dr*dc0.w;
            v[4]=acc[4]*dr*dc1.x; v[5]=acc[5]*dr*dc1.y;
            v[6]=acc[6]*dr*dc1.z; v[7]=acc[7]*dr*dc1.w;

            v4f w0 = { v[0], v[1], v[2], v[3] };
            v4f w1 = { v[4], v[5], v[6], v[7] };
            size_t ob = (size_t)x * 64 + i * 8;
            __builtin_nontemporal_store(w0, (v4f*)&out[ob]);
            __builtin_nontemporal_store(w1, (v4f*)&out[ob + 4]);

            if (cls == 2) {
                // out[f] = transpose(out[x]) (normalization symmetric).
#pragma unroll
                for (int m = 1; m < 8; m <<= 1) {
#pragma unroll
                    for (int j = 0; j < 8; ++j) {
                        if ((j & m) == 0) {
                            float sel = (i & m) ? v[j] : v[j | m];
                            float got = __shfl_xor(sel, m);
                            float nj  = (i & m) ? got : v[j];
                            float njm = (i & m) ? v[j | m] : got;
                            v[j] = nj;  v[j | m] = njm;
                        }
                    }
                }
                v4f u0 = { v[0], v[1], v[2], v[3] };
                v4f u1 = { v[4], v[5], v[6], v[7] };
                size_t fb_ = (size_t)f * 64 + i * 8;
                __builtin_nontemporal_store(u0, (v4f*)&out[fb_]);
                __builtin_nontemporal_store(u1, (v4f*)&out[fb_ + 4]);
            }
        }
    }
}

extern "C" void kernel_launch(void* const* d_in, const int* in_sizes, int n_in,
                              void* d_out, int out_size, void* d_ws, size_t ws_size,
                              hipStream_t stream) {
    const float* F  = (const float*)d_in[0];
    const int*   ei = (const int*)d_in[1];
    const int E = in_sizes[1] / 2;
    const int* row = ei;
    const int* col = ei + E;
    const int EH = E / 2;
    const int NBD = (EH + 31) / 32;               // deg pair-blocks
    const int NBI = (E + 255) / 256;              // insert blocks
    const int TB  = NBD + NBI;
    const int M   = (TB / NBI > 1) ? (TB / NBI) : 1;   // role interleave period
    const int nflag = (E + 31) / 32;

    // workspace layout (~9.4 MB)
    unsigned long long* slots = (unsigned long long*)d_ws;          // 8 MB
    uint32_t* flags = (uint32_t*)(slots + HSIZE);                   // ~64 KB
    float*    deg   = (float*)(flags + nflag);
    float*    dinv  = deg + ND;
    float*    out   = (float*)d_out;

    k_fill     <<<(HSIZE / 2 + 255) / 256, 256, 0, stream>>>(slots, deg, flags, nflag);
    k_work     <<<TB,               256, 0, stream>>>(F, row, col, slots, flags, deg, E, EH, NBI, M);
    k_fixdeg   <<<(E + 255) / 256,  256, 0, stream>>>(F, row, col, slots, flags, deg, E, EH);
    k_dinv_diag<<<(ND + 255) / 256, 256, 0, stream>>>(deg, dinv, out, E);
    k_pnorm_opt<<<NBD,              256, 0, stream>>>(F, row, col, slots, flags, dinv, out, E, EH);
}

// Round 12
// 145.181 us; speedup vs baseline: 1.1234x; 1.1234x over previous
//
#include <hip/hip_runtime.h>
#include <stdint.h>

// ---------------- problem constants (from reference) ----------------
constexpr int NN   = 20000;          // N_NODES
constexpr int DD   = 8;              // D
constexpr int ND   = NN * DD;        // 160000 block-rows
constexpr uint32_t HSIZE = 1u << 20; // 1,048,576 slots for 500k keys
constexpr uint32_t HMASK = HSIZE - 1;
// packed slot: (key << 19) | edge_idx.  key < 2^29, idx < 2^19. EMPTY = all-ones.
constexpr unsigned long long EMPTY64 = ~0ULL;

typedef float v4f __attribute__((ext_vector_type(4)));

__device__ __forceinline__ uint32_t hkey(uint32_t k) {
    k *= 2654435761u;
    return k ^ (k >> 15);
}

__device__ __forceinline__ int hprobe(const unsigned long long* __restrict__ slots,
                                      uint32_t key, int fallback) {
    uint32_t s = hkey(key) & HMASK;
    while (true) {
        unsigned long long v = slots[s];
        if (v == EMPTY64) return fallback;
        if ((uint32_t)(v >> 19) == key) return (int)(v & 0x7FFFFu);
        s = (s + 1) & HMASK;
    }
}

// 8x8 MAC: acc[k] += F_a[j][i] * F_b[j][k]  (P = A^T B, lane owns row i)
__device__ __forceinline__ void mac8(const float* __restrict__ fav,
                                     const float* __restrict__ fbv,
                                     int i, float* __restrict__ acc) {
#pragma unroll
    for (int j = 0; j < 8; ++j) {
        float  a  = fav[j * 8 + i];
        float4 b0 = *(const float4*)&fbv[j * 8];
        float4 b1 = *(const float4*)&fbv[j * 8 + 4];
        acc[0] = fmaf(a, b0.x, acc[0]);  acc[1] = fmaf(a, b0.y, acc[1]);
        acc[2] = fmaf(a, b0.z, acc[2]);  acc[3] = fmaf(a, b0.w, acc[3]);
        acc[4] = fmaf(a, b1.x, acc[4]);  acc[5] = fmaf(a, b1.y, acc[5]);
        acc[6] = fmaf(a, b1.z, acc[6]);  acc[7] = fmaf(a, b1.w, acc[7]);
    }
}

// ---------------- fill: slots=EMPTY (16B stores) + deg=1 ------------------
__global__ void k_fill(unsigned long long* __restrict__ slots,
                       float* __restrict__ deg) {
    uint32_t i = blockIdx.x * blockDim.x + threadIdx.x;
    if (i < HSIZE / 2) {
        ulonglong2 v; v.x = EMPTY64; v.y = EMPTY64;
        ((ulonglong2*)slots)[i] = v;
    }
    if (i < (uint32_t)ND) deg[i] = 1.0f;
}

// ---------------- insert: single fused atomicMin64 per probe --------------
__global__ void k_insert(const int* __restrict__ row, const int* __restrict__ col,
                         unsigned long long* __restrict__ slots, int E) {
    int e = blockIdx.x * blockDim.x + threadIdx.x;
    if (e >= E) return;
    uint32_t key = (uint32_t)(row[e] * NN + col[e]);
    unsigned long long cur = ((unsigned long long)key << 19) | (unsigned)e;
    uint32_t s = hkey(key) & HMASK;
    while (true) {
        unsigned long long old = atomicMin(&slots[s], cur);
        if (old == EMPTY64) break;
        if ((uint32_t)(old >> 19) == key) break;
        if (old > cur) { cur = old; key = (uint32_t)(cur >> 19); }
        s = (s + 1) & HMASK;
    }
}

// ---------------- pass A: probe+classify+deg, pair-structured blocks ------
__global__ void __launch_bounds__(256)
k_deg(const float* __restrict__ F,
      const int* __restrict__ row, const int* __restrict__ col,
      const unsigned long long* __restrict__ slots, int* __restrict__ task,
      float* __restrict__ deg, int E, int EH) {
    __shared__ float fa[64 * 68];
    __shared__ int s_x[64], s_me[64], s_f[64], s_cls[64], s_row[64], s_col[64];
    const int t  = threadIdx.x;
    const int b0 = blockIdx.x * 32;

    if (t < 64) {
        int s = t;
        int x = (s < 32) ? (b0 + s) : (EH + b0 + (s - 32));
        bool valid = (s < 32) ? (x < EH) : (x < E);
        int r = 0, c = 0, me = -1;
        if (valid) {
            r = row[x]; c = col[x];
            me = hprobe(slots, (uint32_t)(r * NN + c), x);   // L(own key)
        } else x = -1;
        s_x[s] = x; s_row[s] = r; s_col[s] = c; s_me[s] = me;
    }
    __syncthreads();

    if (t < 64) {                    // classify: partner probe-share or fallback
        int s = t, x = s_x[s];
        int cls = 0, f = 0;
        if (x >= 0) {
            int q = s ^ 32;
            int r = s_row[s], c = s_col[s], me = s_me[s];
            if (s_x[q] >= 0 && s_row[q] == c && s_col[q] == r) f = s_me[q];
            else f = hprobe(slots, (uint32_t)(c * NN + r), x);
            cls = (f == x) ? 1 : ((me == x) ? ((x < f) ? 2 : 0) : 1);
            task[x] = f | (cls << 29);
        }
        s_f[s] = f; s_cls[s] = cls;
    }

    // stage all 64 slots' F blocks (sequential, coalesced; no gather)
    const float4* F4 = (const float4*)F;
#pragma unroll
    for (int p = 0; p < 4; ++p) {
        int q = t + p * 256;                     // 0..1023
        int sl = q >> 4, sub = q & 15;
        int x = s_x[sl];
        if (x >= 0)
            *(float4*)&fa[sl * 68 + (sub << 2)] = F4[(size_t)x * 16 + sub];
    }
    __syncthreads();

    const int g = t >> 3, i = t & 7;
#pragma unroll
    for (int item = 0; item < 2; ++item) {
        int s = (item == 0) ? g : (g + 32);
        int q = s ^ 32;
        int x = s_x[s];
        int cls = (x >= 0) ? s_cls[s] : 0;
        if (cls) {
            int f = s_f[s];
            const float* fav = &fa[s * 68];
            float acc[8] = {0,0,0,0,0,0,0,0};
            const float* lsrc = (f == s_x[q]) ? &fa[q * 68] : ((f == x) ? fav : nullptr);
            if (lsrc) mac8(fav, lsrc, i, acc);
            else      mac8(fav, F + (size_t)f * 64, i, acc);   // rare (dups)
            float b0f=fabsf(acc[0]),b1=fabsf(acc[1]),b2=fabsf(acc[2]),b3=fabsf(acc[3]);
            float b4=fabsf(acc[4]),b5=fabsf(acc[5]),b6=fabsf(acc[6]),b7=fabsf(acc[7]);
            atomicAdd(&deg[s_row[s] * DD + i], b0f+b1+b2+b3+b4+b5+b6+b7);
            if (cls == 2) {        // partner rowsum = our colsum (P_f = P_e^T)
#pragma unroll
                for (int m = 1; m < 8; m <<= 1) {
                    b0f+=__shfl_xor(b0f,m); b1+=__shfl_xor(b1,m);
                    b2 +=__shfl_xor(b2,m);  b3+=__shfl_xor(b3,m);
                    b4 +=__shfl_xor(b4,m);  b5+=__shfl_xor(b5,m);
                    b6 +=__shfl_xor(b6,m);  b7+=__shfl_xor(b7,m);
                }
                float ci = (i&4) ? ((i&2)?((i&1)?b7:b6):((i&1)?b5:b4))
                                 : ((i&2)?((i&1)?b3:b2):((i&1)?b1:b0f));
                atomicAdd(&deg[s_col[s] * DD + i], ci);
            }
        }
    }
}

// ---------------- dinv = deg^-0.5 AND diagonal blocks of out --------------
__global__ void k_dinv_diag(const float* __restrict__ deg, float* __restrict__ dinv,
                            float* __restrict__ out, int E) {
    int r = blockIdx.x * blockDim.x + threadIdx.x;
    if (r >= ND) return;
    float dv = 1.0f / sqrtf(deg[r]);
    dinv[r] = dv;
    float dd = dv * dv;
    int i = r & 7;
    v4f a = { 0.f, 0.f, 0.f, 0.f };
    v4f b = { 0.f, 0.f, 0.f, 0.f };
    if (i < 4) a[i] = dd; else b[i - 4] = dd;
    size_t base = (size_t)E * 64 + (size_t)(r >> 3) * 64 + (size_t)i * 8;
    *(v4f*)&out[base]     = a;        // normal stores: let L3 absorb
    *(v4f*)&out[base + 4] = b;
}

// ---------------- pass B: recompute P (pair-staged), normalize, write -----
__global__ void __launch_bounds__(256)
k_pnorm(const float* __restrict__ F,
        const int* __restrict__ row, const int* __restrict__ col,
        const int* __restrict__ task, const float* __restrict__ dinv,
        float* __restrict__ out, int E, int EH) {
    __shared__ float fa[64 * 68];
    __shared__ int s_x[64], s_f[64], s_cls[64], s_row[64], s_col[64];
    const int t  = threadIdx.x;
    const int b0 = blockIdx.x * 32;

    if (t < 64) {
        int s = t;
        int x = (s < 32) ? (b0 + s) : (EH + b0 + (s - 32));
        bool valid = (s < 32) ? (x < EH) : (x < E);
        int cls = 0, f = 0, r = 0, c = 0;
        if (valid) {
            int w = task[x];
            cls = w >> 29;
            f   = w & ((1 << 29) - 1);
            r = row[x]; c = col[x];
        } else x = -1;
        s_x[s] = x; s_f[s] = f; s_cls[s] = cls; s_row[s] = r; s_col[s] = c;
    }
    __syncthreads();

    const float4* F4 = (const float4*)F;
#pragma unroll
    for (int p = 0; p < 4; ++p) {
        int q = t + p * 256;
        int sl = q >> 4, sub = q & 15;
        int x = s_x[sl];
        if (x >= 0)
            *(float4*)&fa[sl * 68 + (sub << 2)] = F4[(size_t)x * 16 + sub];
    }
    __syncthreads();

    const int g = t >> 3, i = t & 7;
#pragma unroll
    for (int item = 0; item < 2; ++item) {
        int s = (item == 0) ? g : (g + 32);
        int q = s ^ 32;
        int x = s_x[s];
        int cls = (x >= 0) ? s_cls[s] : 0;
        if (cls) {
            int f = s_f[s];
            const float* fav = &fa[s * 68];
            float acc[8] = {0,0,0,0,0,0,0,0};
            const float* lsrc = (f == s_x[q]) ? &fa[q * 68] : ((f == x) ? fav : nullptr);
            if (lsrc) mac8(fav, lsrc, i, acc);
            else      mac8(fav, F + (size_t)f * 64, i, acc);

            const int r = s_row[s], c = s_col[s];
            float dr = dinv[r * DD + i];
            v4f dc0 = *(const v4f*)&dinv[c * DD];
            v4f dc1 = *(const v4f*)&dinv[c * DD + 4];

            float v[8];
            v[0]=acc[0]*dr*dc0.x; v[1]=acc[1]*dr*dc0.y;
            v[2]=acc[2]*dr*dc0.z; v[3]=acc[3]*dr*dc0.w;
            v[4]=acc[4]*dr*dc1.x; v[5]=acc[5]*dr*dc1.y;
            v[6]=acc[6]*dr*dc1.z; v[7]=acc[7]*dr*dc1.w;

            v4f w0 = { v[0], v[1], v[2], v[3] };
            v4f w1 = { v[4], v[5], v[6], v[7] };
            size_t ob = (size_t)x * 64 + i * 8;
            *(v4f*)&out[ob]     = w0;         // normal stores: L3 absorbs
            *(v4f*)&out[ob + 4] = w1;

            if (cls == 2) {
                // out[f] = transpose(out[x]) (normalization symmetric).
#pragma unroll
                for (int m = 1; m < 8; m <<= 1) {
#pragma unroll
                    for (int j = 0; j < 8; ++j) {
                        if ((j & m) == 0) {
                            float sel = (i & m) ? v[j] : v[j | m];
                            float got = __shfl_xor(sel, m);
                            float nj  = (i & m) ? got : v[j];
                            float njm = (i & m) ? v[j | m] : got;
                            v[j] = nj;  v[j | m] = njm;
                        }
                    }
                }
                v4f u0 = { v[0], v[1], v[2], v[3] };
                v4f u1 = { v[4], v[5], v[6], v[7] };
                size_t fb_ = (size_t)f * 64 + i * 8;
                *(v4f*)&out[fb_]     = u0;
                *(v4f*)&out[fb_ + 4] = u1;
            }
        }
    }
}

extern "C" void kernel_launch(void* const* d_in, const int* in_sizes, int n_in,
                              void* d_out, int out_size, void* d_ws, size_t ws_size,
                              hipStream_t stream) {
    const float* F  = (const float*)d_in[0];
    const int*   ei = (const int*)d_in[1];
    const int E = in_sizes[1] / 2;
    const int* row = ei;
    const int* col = ei + E;
    const int EH = E / 2;
    const int NB = ((E - EH) + 31) / 32;      // pair-block grid

    // workspace layout (~11.9 MB)
    unsigned long long* slots = (unsigned long long*)d_ws;          // 8 MB
    int*   task = (int*)(slots + HSIZE);
    float* deg  = (float*)(task + E);
    float* dinv = deg + ND;
    float* out  = (float*)d_out;

    k_fill     <<<(HSIZE / 2 + 255) / 256, 256, 0, stream>>>(slots, deg);
    k_insert   <<<(E + 255) / 256,  256, 0, stream>>>(row, col, slots, E);
    k_deg      <<<NB,               256, 0, stream>>>(F, row, col, slots, task, deg, E, EH);
    k_dinv_diag<<<(ND + 255) / 256, 256, 0, stream>>>(deg, dinv, out, E);
    k_pnorm    <<<NB,               256, 0, stream>>>(F, row, col, task, dinv, out, E, EH);
}

// Round 13
// 140.412 us; speedup vs baseline: 1.1615x; 1.0340x over previous
//
#include <hip/hip_runtime.h>
#include <stdint.h>

// ---------------- problem constants (from reference) ----------------
constexpr int NN   = 20000;          // N_NODES
constexpr int DD   = 8;              // D
constexpr int ND   = NN * DD;        // 160000 block-rows
constexpr uint32_t HSIZE = 1u << 20; // 1,048,576 slots for 500k keys
constexpr uint32_t HMASK = HSIZE - 1;
// packed slot: (key << 19) | edge_idx.  key < 2^29, idx < 2^19. EMPTY = all-ones.
constexpr unsigned long long EMPTY64 = ~0ULL;

typedef float v4f __attribute__((ext_vector_type(4)));

__device__ __forceinline__ uint32_t hkey(uint32_t k) {
    k *= 2654435761u;
    return k ^ (k >> 15);
}

__device__ __forceinline__ int hprobe(const unsigned long long* __restrict__ slots,
                                      uint32_t key, int fallback) {
    uint32_t s = hkey(key) & HMASK;
    while (true) {
        unsigned long long v = slots[s];
        if (v == EMPTY64) return fallback;
        if ((uint32_t)(v >> 19) == key) return (int)(v & 0x7FFFFu);
        s = (s + 1) & HMASK;
    }
}

// 8x8 MAC: acc[k] += F_a[j][i] * F_b[j][k]  (P = A^T B, lane owns row i)
__device__ __forceinline__ void mac8(const float* __restrict__ fav,
                                     const float* __restrict__ fbv,
                                     int i, float* __restrict__ acc) {
#pragma unroll
    for (int j = 0; j < 8; ++j) {
        float  a  = fav[j * 8 + i];
        float4 b0 = *(const float4*)&fbv[j * 8];
        float4 b1 = *(const float4*)&fbv[j * 8 + 4];
        acc[0] = fmaf(a, b0.x, acc[0]);  acc[1] = fmaf(a, b0.y, acc[1]);
        acc[2] = fmaf(a, b0.z, acc[2]);  acc[3] = fmaf(a, b0.w, acc[3]);
        acc[4] = fmaf(a, b1.x, acc[4]);  acc[5] = fmaf(a, b1.y, acc[5]);
        acc[6] = fmaf(a, b1.z, acc[6]);  acc[7] = fmaf(a, b1.w, acc[7]);
    }
}

// ---------------- fill: slots=EMPTY (16B stores) + deg=1 ------------------
__global__ void k_fill(unsigned long long* __restrict__ slots,
                       float* __restrict__ deg) {
    uint32_t i = blockIdx.x * blockDim.x + threadIdx.x;
    if (i < HSIZE / 2) {
        ulonglong2 v; v.x = EMPTY64; v.y = EMPTY64;
        ((ulonglong2*)slots)[i] = v;
    }
    if (i < (uint32_t)ND) deg[i] = 1.0f;
}

// ---------------- insert: single fused atomicMin64 per probe --------------
__global__ void k_insert(const int* __restrict__ row, const int* __restrict__ col,
                         unsigned long long* __restrict__ slots, int E) {
    int e = blockIdx.x * blockDim.x + threadIdx.x;
    if (e >= E) return;
    uint32_t key = (uint32_t)(row[e] * NN + col[e]);
    unsigned long long cur = ((unsigned long long)key << 19) | (unsigned)e;
    uint32_t s = hkey(key) & HMASK;
    while (true) {
        unsigned long long old = atomicMin(&slots[s], cur);
        if (old == EMPTY64) break;
        if ((uint32_t)(old >> 19) == key) break;
        if (old > cur) { cur = old; key = (uint32_t)(cur >> 19); }
        s = (s + 1) & HMASK;
    }
}

// ---------------- pass A: probe+classify+deg, pair-structured blocks ------
__global__ void __launch_bounds__(256)
k_deg(const float* __restrict__ F,
      const int* __restrict__ row, const int* __restrict__ col,
      const unsigned long long* __restrict__ slots, int* __restrict__ task,
      float* __restrict__ deg, int E, int EH) {
    __shared__ float fa[64 * 68];
    __shared__ int s_x[64], s_me[64], s_f[64], s_cls[64], s_row[64], s_col[64];
    const int t  = threadIdx.x;
    const int b0 = blockIdx.x * 32;

    if (t < 64) {
        int s = t;
        int x = (s < 32) ? (b0 + s) : (EH + b0 + (s - 32));
        bool valid = (s < 32) ? (x < EH) : (x < E);
        int r = 0, c = 0, me = -1;
        if (valid) {
            r = row[x]; c = col[x];
            me = hprobe(slots, (uint32_t)(r * NN + c), x);   // L(own key)
        } else x = -1;
        s_x[s] = x; s_row[s] = r; s_col[s] = c; s_me[s] = me;
    }
    __syncthreads();

    if (t < 64) {                    // classify: partner probe-share or fallback
        int s = t, x = s_x[s];
        int cls = 0, f = 0;
        if (x >= 0) {
            int q = s ^ 32;
            int r = s_row[s], c = s_col[s], me = s_me[s];
            if (s_x[q] >= 0 && s_row[q] == c && s_col[q] == r) f = s_me[q];
            else f = hprobe(slots, (uint32_t)(c * NN + r), x);
            cls = (f == x) ? 1 : ((me == x) ? ((x < f) ? 2 : 0) : 1);
            task[x] = f | (cls << 29);
        }
        s_f[s] = f; s_cls[s] = cls;
    }

    // stage all 64 slots' F blocks (sequential, coalesced; no gather)
    const float4* F4 = (const float4*)F;
#pragma unroll
    for (int p = 0; p < 4; ++p) {
        int q = t + p * 256;                     // 0..1023
        int sl = q >> 4, sub = q & 15;
        int x = s_x[sl];
        if (x >= 0)
            *(float4*)&fa[sl * 68 + (sub << 2)] = F4[(size_t)x * 16 + sub];
    }
    __syncthreads();

    const int g = t >> 3, i = t & 7;
#pragma unroll
    for (int item = 0; item < 2; ++item) {
        int s = (item == 0) ? g : (g + 32);
        int q = s ^ 32;
        int x = s_x[s];
        int cls = (x >= 0) ? s_cls[s] : 0;
        if (cls) {
            int f = s_f[s];
            const float* fav = &fa[s * 68];
            float acc[8] = {0,0,0,0,0,0,0,0};
            const float* lsrc = (f == s_x[q]) ? &fa[q * 68] : ((f == x) ? fav : nullptr);
            if (lsrc) mac8(fav, lsrc, i, acc);
            else      mac8(fav, F + (size_t)f * 64, i, acc);   // rare (dups)
            float b0f=fabsf(acc[0]),b1=fabsf(acc[1]),b2=fabsf(acc[2]),b3=fabsf(acc[3]);
            float b4=fabsf(acc[4]),b5=fabsf(acc[5]),b6=fabsf(acc[6]),b7=fabsf(acc[7]);
            atomicAdd(&deg[s_row[s] * DD + i], b0f+b1+b2+b3+b4+b5+b6+b7);
            if (cls == 2) {        // partner rowsum = our colsum (P_f = P_e^T)
#pragma unroll
                for (int m = 1; m < 8; m <<= 1) {
                    b0f+=__shfl_xor(b0f,m); b1+=__shfl_xor(b1,m);
                    b2 +=__shfl_xor(b2,m);  b3+=__shfl_xor(b3,m);
                    b4 +=__shfl_xor(b4,m);  b5+=__shfl_xor(b5,m);
                    b6 +=__shfl_xor(b6,m);  b7+=__shfl_xor(b7,m);
                }
                float ci = (i&4) ? ((i&2)?((i&1)?b7:b6):((i&1)?b5:b4))
                                 : ((i&2)?((i&1)?b3:b2):((i&1)?b1:b0f));
                atomicAdd(&deg[s_col[s] * DD + i], ci);
            }
        }
    }
}

// ---------------- pass B: recompute P, normalize inline from deg, write ---
// Grid = NB pair-blocks + ceil(ND/256) diag-blocks (dinv kernel folded in).
__global__ void __launch_bounds__(256)
k_pnorm(const float* __restrict__ F,
        const int* __restrict__ row, const int* __restrict__ col,
        const int* __restrict__ task, const float* __restrict__ deg,
        float* __restrict__ out, int E, int EH, int NB) {
    const int t = threadIdx.x;

    if ((int)blockIdx.x >= NB) {           // ---- diag role: dd = 1/deg ----
        int r = (blockIdx.x - NB) * 256 + t;
        if (r >= ND) return;
        float dd = 1.0f / deg[r];          // (deg^-1/2)^2 exactly
        int i = r & 7;
        v4f a = { 0.f, 0.f, 0.f, 0.f };
        v4f b = { 0.f, 0.f, 0.f, 0.f };
        if (i < 4) a[i] = dd; else b[i - 4] = dd;
        size_t base = (size_t)E * 64 + (size_t)(r >> 3) * 64 + (size_t)i * 8;
        *(v4f*)&out[base]     = a;
        *(v4f*)&out[base + 4] = b;
        return;
    }

    __shared__ float fa[64 * 68];
    __shared__ int s_x[64], s_f[64], s_cls[64], s_row[64], s_col[64];
    const int b0 = blockIdx.x * 32;

    if (t < 64) {
        int s = t;
        int x = (s < 32) ? (b0 + s) : (EH + b0 + (s - 32));
        bool valid = (s < 32) ? (x < EH) : (x < E);
        int cls = 0, f = 0, r = 0, c = 0;
        if (valid) {
            int w = task[x];
            cls = w >> 29;
            f   = w & ((1 << 29) - 1);
            r = row[x]; c = col[x];
        } else x = -1;
        s_x[s] = x; s_f[s] = f; s_cls[s] = cls; s_row[s] = r; s_col[s] = c;
    }
    __syncthreads();

    const float4* F4 = (const float4*)F;
#pragma unroll
    for (int p = 0; p < 4; ++p) {
        int q = t + p * 256;
        int sl = q >> 4, sub = q & 15;
        int x = s_x[sl];
        if (x >= 0)
            *(float4*)&fa[sl * 68 + (sub << 2)] = F4[(size_t)x * 16 + sub];
    }
    __syncthreads();

    const int g = t >> 3, i = t & 7;
#pragma unroll
    for (int item = 0; item < 2; ++item) {
        int s = (item == 0) ? g : (g + 32);
        int q = s ^ 32;
        int x = s_x[s];
        int cls = (x >= 0) ? s_cls[s] : 0;
        if (cls) {
            int f = s_f[s];
            const float* fav = &fa[s * 68];
            float acc[8] = {0,0,0,0,0,0,0,0};
            const float* lsrc = (f == s_x[q]) ? &fa[q * 68] : ((f == x) ? fav : nullptr);
            if (lsrc) mac8(fav, lsrc, i, acc);
            else      mac8(fav, F + (size_t)f * 64, i, acc);

            const int r = s_row[s], c = s_col[s];
            float dr = 1.0f / sqrtf(deg[r * DD + i]);     // dinv inline
            v4f dg0 = *(const v4f*)&deg[c * DD];
            v4f dg1 = *(const v4f*)&deg[c * DD + 4];
            v4f dc0, dc1;
            dc0.x = 1.0f / sqrtf(dg0.x);  dc0.y = 1.0f / sqrtf(dg0.y);
            dc0.z = 1.0f / sqrtf(dg0.z);  dc0.w = 1.0f / sqrtf(dg0.w);
            dc1.x = 1.0f / sqrtf(dg1.x);  dc1.y = 1.0f / sqrtf(dg1.y);
            dc1.z = 1.0f / sqrtf(dg1.z);  dc1.w = 1.0f / sqrtf(dg1.w);

            float v[8];
            v[0]=acc[0]*dr*dc0.x; v[1]=acc[1]*dr*dc0.y;
            v[2]=acc[2]*dr*dc0.z; v[3]=acc[3]*dr*dc0.w;
            v[4]=acc[4]*dr*dc1.x; v[5]=acc[5]*dr*dc1.y;
            v[6]=acc[6]*dr*dc1.z; v[7]=acc[7]*dr*dc1.w;

            v4f w0 = { v[0], v[1], v[2], v[3] };
            v4f w1 = { v[4], v[5], v[6], v[7] };
            size_t ob = (size_t)x * 64 + i * 8;
            *(v4f*)&out[ob]     = w0;
            *(v4f*)&out[ob + 4] = w1;

            if (cls == 2) {
                // out[f] = transpose(out[x]) (normalization symmetric).
#pragma unroll
                for (int m = 1; m < 8; m <<= 1) {
#pragma unroll
                    for (int j = 0; j < 8; ++j) {
                        if ((j & m) == 0) {
                            float sel = (i & m) ? v[j] : v[j | m];
                            float got = __shfl_xor(sel, m);
                            float nj  = (i & m) ? got : v[j];
                            float njm = (i & m) ? v[j | m] : got;
                            v[j] = nj;  v[j | m] = njm;
                        }
                    }
                }
                v4f u0 = { v[0], v[1], v[2], v[3] };
                v4f u1 = { v[4], v[5], v[6], v[7] };
                size_t fb_ = (size_t)f * 64 + i * 8;
                *(v4f*)&out[fb_]     = u0;
                *(v4f*)&out[fb_ + 4] = u1;
            }
        }
    }
}

extern "C" void kernel_launch(void* const* d_in, const int* in_sizes, int n_in,
                              void* d_out, int out_size, void* d_ws, size_t ws_size,
                              hipStream_t stream) {
    const float* F  = (const float*)d_in[0];
    const int*   ei = (const int*)d_in[1];
    const int E = in_sizes[1] / 2;
    const int* row = ei;
    const int* col = ei + E;
    const int EH = E / 2;
    const int NB = ((E - EH) + 31) / 32;      // pair-block grid
    const int NDIAG = (ND + 255) / 256;       // diag blocks appended to pnorm

    // workspace layout (~11.3 MB)
    unsigned long long* slots = (unsigned long long*)d_ws;          // 8 MB
    int*   task = (int*)(slots + HSIZE);
    float* deg  = (float*)(task + E);
    float* out  = (float*)d_out;

    k_fill  <<<(HSIZE / 2 + 255) / 256, 256, 0, stream>>>(slots, deg);
    k_insert<<<(E + 255) / 256,  256, 0, stream>>>(row, col, slots, E);
    k_deg   <<<NB,               256, 0, stream>>>(F, row, col, slots, task, deg, E, EH);
    k_pnorm <<<NB + NDIAG,       256, 0, stream>>>(F, row, col, task, deg, out, E, EH, NB);
}